// Round 3
// baseline (498.861 us; speedup 1.0000x reference)
//
#include <hip/hip_runtime.h>
#include <math.h>

#define SIGMA_C   1e-4f
#define GAMMA_C   1e-4f
#define ZNEAR_C   1.0f
#define ZFAR_C    100.0f
#define EPSB_C    1e-10f

static constexpr int N_ = 8, H_ = 512, W_ = 512, K_ = 4;
static constexpr int NPIX = N_ * H_ * W_;   // 2,097,152
static constexpr int HW_SHIFT = 18;         // H_*W_ = 2^18

// clang-native vector types (accepted by __builtin_nontemporal_load)
typedef float fvec4 __attribute__((ext_vector_type(4)));
typedef int   ivec4 __attribute__((ext_vector_type(4)));

struct F3 { float x, y, z; };   // 12B contiguous -> global_load_dwordx3
struct I3 { int   x, y, z; };

__device__ __forceinline__ fvec4 ntload_f4(const float* p) {
    return __builtin_nontemporal_load(reinterpret_cast<const fvec4*>(p));
}
__device__ __forceinline__ ivec4 ntload_i4(const int* p) {
    return __builtin_nontemporal_load(reinterpret_cast<const ivec4*>(p));
}

__global__ __launch_bounds__(256) void soft_phong_kernel(
    const float* __restrict__ verts,
    const float* __restrict__ vnorm,
    const float* __restrict__ bary,
    const float* __restrict__ zbuf,
    const float* __restrict__ dists,
    const float* __restrict__ texels,
    const float* __restrict__ vis,
    const float* __restrict__ l_loc,
    const float* __restrict__ l_amb,
    const float* __restrict__ l_dif,
    const float* __restrict__ l_spec,
    const float* __restrict__ cam,
    const float* __restrict__ m_amb,
    const float* __restrict__ m_dif,
    const float* __restrict__ m_spec,
    const float* __restrict__ shininess,
    const int*   __restrict__ faces,
    const int*   __restrict__ p2f,
    float* __restrict__ out)
{
    const int p = blockIdx.x * 256 + threadIdx.x;
    const int n = p >> HW_SHIFT;

    // ---- streaming per-pixel loads (coalesced, nontemporal: read-once) ----
    const ivec4 f4 = ntload_i4(p2f + 4*p);
    const fvec4 z4 = ntload_f4(zbuf + 4*p);
    const fvec4 d4 = ntload_f4(dists + 4*p);
    const fvec4 bA = ntload_f4(bary + 12*p + 0);
    const fvec4 bB = ntload_f4(bary + 12*p + 4);
    const fvec4 bC = ntload_f4(bary + 12*p + 8);
    const fvec4 tA = ntload_f4(texels + 12*p + 0);
    const fvec4 tB = ntload_f4(texels + 12*p + 4);
    const fvec4 tC = ntload_f4(texels + 12*p + 8);
    const float vR = __builtin_nontemporal_load(vis + 3*p+0);
    const float vG = __builtin_nontemporal_load(vis + 3*p+1);
    const float vB = __builtin_nontemporal_load(vis + 3*p+2);

    const int fi[4] = {f4.x, f4.y, f4.z, f4.w};

    // ---- unconditional gathers: clamp masked indices to 0 (real data, w=0 later)
    // All 4 face-index loads issue together, then all 24 dwordx3 vertex loads
    // are in flight simultaneously -> ~4x MLP vs the branchy version.
    I3 fidx[4];
#pragma unroll
    for (int k = 0; k < 4; ++k) {
        const int f = (fi[k] >= 0) ? fi[k] : 0;
        fidx[k] = reinterpret_cast<const I3*>(faces)[f];
    }

    F3 vp[4][3], vn[4][3];
#pragma unroll
    for (int k = 0; k < 4; ++k) {
        const int i0 = fidx[k].x, i1 = fidx[k].y, i2 = fidx[k].z;
        vp[k][0] = reinterpret_cast<const F3*>(verts)[i0];
        vp[k][1] = reinterpret_cast<const F3*>(verts)[i1];
        vp[k][2] = reinterpret_cast<const F3*>(verts)[i2];
        vn[k][0] = reinterpret_cast<const F3*>(vnorm)[i0];
        vn[k][1] = reinterpret_cast<const F3*>(vnorm)[i1];
        vn[k][2] = reinterpret_cast<const F3*>(vnorm)[i2];
    }

    // ---- per-batch uniforms (scalar loads, block-uniform n) ----
    const float llx = l_loc[3*n+0], lly = l_loc[3*n+1], llz = l_loc[3*n+2];
    const float ccx = cam[3*n+0],   ccy = cam[3*n+1],   ccz = cam[3*n+2];
    const float ambR = m_amb[3*n+0]*l_amb[3*n+0];
    const float ambG = m_amb[3*n+1]*l_amb[3*n+1];
    const float ambB = m_amb[3*n+2]*l_amb[3*n+2];
    const float kdR  = m_dif[3*n+0]*l_dif[3*n+0];
    const float kdG  = m_dif[3*n+1]*l_dif[3*n+1];
    const float kdB  = m_dif[3*n+2]*l_dif[3*n+2];
    const float ksR  = m_spec[3*n+0]*l_spec[3*n+0];
    const float ksG  = m_spec[3*n+1]*l_spec[3*n+1];
    const float ksB  = m_spec[3*n+2]*l_spec[3*n+2];
    const float shin = shininess[n];

    const float zb[4] = {z4.x, z4.y, z4.z, z4.w};
    const float dd[4] = {d4.x, d4.y, d4.z, d4.w};
    const float bc[12] = {bA.x,bA.y,bA.z,bA.w, bB.x,bB.y,bB.z,bB.w, bC.x,bC.y,bC.z,bC.w};
    const float tx[12] = {tA.x,tA.y,tA.z,tA.w, tB.x,tB.y,tB.z,tB.w, tC.x,tC.y,tC.z,tC.w};

    float colR[4], colG[4], colB[4], prob[4], zinv[4];
    float zmax = EPSB_C;

#pragma unroll
    for (int k = 0; k < 4; ++k) {
        const bool live = fi[k] >= 0;
        const float b0 = bc[3*k+0], b1 = bc[3*k+1], b2 = bc[3*k+2];

        const float pcx = b0*vp[k][0].x + b1*vp[k][1].x + b2*vp[k][2].x;
        const float pcy = b0*vp[k][0].y + b1*vp[k][1].y + b2*vp[k][2].y;
        const float pcz = b0*vp[k][0].z + b1*vp[k][1].z + b2*vp[k][2].z;

        const float pnx = b0*vn[k][0].x + b1*vn[k][1].x + b2*vn[k][2].x;
        const float pny = b0*vn[k][0].y + b1*vn[k][1].y + b2*vn[k][2].y;
        const float pnz = b0*vn[k][0].z + b1*vn[k][1].z + b2*vn[k][2].z;

        const float nl  = sqrtf(pnx*pnx + pny*pny + pnz*pnz);
        const float inl = 1.0f / fmaxf(nl, 1e-6f);
        const float nx = pnx*inl, ny = pny*inl, nz = pnz*inl;

        float dx = llx - pcx, dy = lly - pcy, dz = llz - pcz;
        const float dl  = sqrtf(dx*dx + dy*dy + dz*dz);
        const float idl = 1.0f / fmaxf(dl, 1e-6f);
        dx *= idl; dy *= idl; dz *= idl;

        const float cosang = nx*dx + ny*dy + nz*dz;
        const float rcos   = fmaxf(cosang, 0.0f);

        const float rx = 2.0f*cosang*nx - dx;
        const float ry = 2.0f*cosang*ny - dy;
        const float rz = 2.0f*cosang*nz - dz;

        float vx = ccx - pcx, vy = ccy - pcy, vz = ccz - pcz;
        const float vl  = sqrtf(vx*vx + vy*vy + vz*vz);
        const float ivl = 1.0f / fmaxf(vl, 1e-6f);
        vx *= ivl; vy *= ivl; vz *= ivl;

        const float sdot = vx*rx + vy*ry + vz*rz;
        const float spec_cos = (cosang > 0.0f) ? fmaxf(sdot, 0.0f) : 0.0f;
        const float sp = (spec_cos > 0.0f) ? exp2f(shin * log2f(spec_cos)) : 0.0f;

        colR[k] = (ambR + kdR*rcos*vR) * tx[3*k+0] + ksR*sp;
        colG[k] = (ambG + kdG*rcos*vG) * tx[3*k+1] + ksG*sp;
        colB[k] = (ambB + kdB*rcos*vB) * tx[3*k+2] + ksB*sp;

        // masked samples: prob=0 and zinv=0 => weight 0, matches reference
        prob[k] = live ? 1.0f / (1.0f + expf(dd[k] / SIGMA_C)) : 0.0f;
        zinv[k] = live ? (ZFAR_C - zb[k]) / (ZFAR_C - ZNEAR_C)  : 0.0f;
        zmax = fmaxf(zmax, zinv[k]);
    }

    const float delta = expf((EPSB_C - zmax) / GAMMA_C);
    float denom = delta;
    float accR = delta, accG = delta, accB = delta;   // delta * BG(1,1,1)
    float keep = 1.0f;
#pragma unroll
    for (int k = 0; k < 4; ++k) {
        const float w = prob[k] * expf((zinv[k] - zmax) / GAMMA_C);
        denom += w;
        accR += w * colR[k];
        accG += w * colG[k];
        accB += w * colB[k];
        keep *= (1.0f - prob[k]);
    }
    const float inv = 1.0f / denom;
    fvec4 res; res.x = accR*inv; res.y = accG*inv; res.z = accB*inv; res.w = 1.0f - keep;
    __builtin_nontemporal_store(res, reinterpret_cast<fvec4*>(out) + p);
}

extern "C" void kernel_launch(void* const* d_in, const int* in_sizes, int n_in,
                              void* d_out, int out_size, void* d_ws, size_t ws_size,
                              hipStream_t stream) {
    const float* verts   = (const float*)d_in[0];
    const float* vnorm   = (const float*)d_in[1];
    const float* bary    = (const float*)d_in[2];
    const float* zbuf    = (const float*)d_in[3];
    const float* dists   = (const float*)d_in[4];
    const float* texels  = (const float*)d_in[5];
    const float* vis     = (const float*)d_in[6];
    const float* l_loc   = (const float*)d_in[7];
    const float* l_amb   = (const float*)d_in[8];
    const float* l_dif   = (const float*)d_in[9];
    const float* l_spec  = (const float*)d_in[10];
    const float* cam     = (const float*)d_in[11];
    const float* m_amb   = (const float*)d_in[12];
    const float* m_dif   = (const float*)d_in[13];
    const float* m_spec  = (const float*)d_in[14];
    const float* shin    = (const float*)d_in[15];
    const int*   faces   = (const int*)d_in[16];
    const int*   p2f     = (const int*)d_in[17];
    float* out = (float*)d_out;

    dim3 grid(NPIX / 256), block(256);
    soft_phong_kernel<<<grid, block, 0, stream>>>(
        verts, vnorm, bary, zbuf, dists, texels, vis,
        l_loc, l_amb, l_dif, l_spec, cam,
        m_amb, m_dif, m_spec, shin, faces, p2f, out);
}

// Round 4
// 410.567 us; speedup vs baseline: 1.2151x; 1.2151x over previous
//
#include <hip/hip_runtime.h>
#include <math.h>

#define SIGMA_C   1e-4f
#define GAMMA_C   1e-4f
#define ZNEAR_C   1.0f
#define ZFAR_C    100.0f
#define EPSB_C    1e-10f

static constexpr int N_ = 8, H_ = 512, W_ = 512, K_ = 4;
static constexpr int NPIX = N_ * H_ * W_;   // 2,097,152
static constexpr int HW_SHIFT = 18;         // H_*W_ = 2^18
static constexpr int F_ = 100000;
static constexpr int REC_F = 20;            // floats per face record (80 B stride)
static constexpr size_t TABLE_BYTES = (size_t)F_ * REC_F * sizeof(float);

typedef float fvec4 __attribute__((ext_vector_type(4)));
typedef float fvec2 __attribute__((ext_vector_type(2)));
typedef int   ivec4 __attribute__((ext_vector_type(4)));

struct F3 { float x, y, z; };
struct I3 { int   x, y, z; };

__device__ __forceinline__ fvec4 ntload_f4(const float* p) {
    return __builtin_nontemporal_load(reinterpret_cast<const fvec4*>(p));
}
__device__ __forceinline__ ivec4 ntload_i4(const int* p) {
    return __builtin_nontemporal_load(reinterpret_cast<const ivec4*>(p));
}

// ---------------- Phase 1: pack faces -> 80B records --------------------
// rec layout (floats): [v0.xyz v1.x][v1.yz v2.xy][v2.z n0.xyz][n1.xyz n2.x][n2.yz][pad2]
__global__ __launch_bounds__(256) void build_face_table(
    const float* __restrict__ verts,
    const float* __restrict__ vnorm,
    const int*   __restrict__ faces,
    float* __restrict__ table)
{
    const int f = blockIdx.x * 256 + threadIdx.x;
    if (f >= F_) return;
    const int i0 = faces[3*f+0], i1 = faces[3*f+1], i2 = faces[3*f+2];
    const F3 a = reinterpret_cast<const F3*>(verts)[i0];
    const F3 b = reinterpret_cast<const F3*>(verts)[i1];
    const F3 c = reinterpret_cast<const F3*>(verts)[i2];
    const F3 p = reinterpret_cast<const F3*>(vnorm)[i0];
    const F3 q = reinterpret_cast<const F3*>(vnorm)[i1];
    const F3 r = reinterpret_cast<const F3*>(vnorm)[i2];
    float* o = table + (size_t)f * REC_F;
    fvec4 r0 = {a.x, a.y, a.z, b.x};
    fvec4 r1 = {b.y, b.z, c.x, c.y};
    fvec4 r2 = {c.z, p.x, p.y, p.z};
    fvec4 r3 = {q.x, q.y, q.z, r.x};
    fvec2 r4 = {r.y, r.z};
    *reinterpret_cast<fvec4*>(o + 0)  = r0;
    *reinterpret_cast<fvec4*>(o + 4)  = r1;
    *reinterpret_cast<fvec4*>(o + 8)  = r2;
    *reinterpret_cast<fvec4*>(o + 12) = r3;
    *reinterpret_cast<fvec2*>(o + 16) = r4;
}

// ---------------- Phase 2: shade + blend --------------------------------
__global__ __launch_bounds__(256) void soft_phong_kernel(
    const float* __restrict__ table,        // (F,20) packed face records
    const float* __restrict__ bary,
    const float* __restrict__ zbuf,
    const float* __restrict__ dists,
    const float* __restrict__ texels,
    const float* __restrict__ vis,
    const float* __restrict__ l_loc,
    const float* __restrict__ l_amb,
    const float* __restrict__ l_dif,
    const float* __restrict__ l_spec,
    const float* __restrict__ cam,
    const float* __restrict__ m_amb,
    const float* __restrict__ m_dif,
    const float* __restrict__ m_spec,
    const float* __restrict__ shininess,
    const int*   __restrict__ p2f,
    float* __restrict__ out)
{
    const int p = blockIdx.x * 256 + threadIdx.x;
    const int n = p >> HW_SHIFT;

    // streaming per-pixel loads (coalesced, read-once -> nontemporal)
    const ivec4 f4 = ntload_i4(p2f + 4*p);
    const fvec4 z4 = ntload_f4(zbuf + 4*p);
    const fvec4 d4 = ntload_f4(dists + 4*p);
    const fvec4 bA = ntload_f4(bary + 12*p + 0);
    const fvec4 bB = ntload_f4(bary + 12*p + 4);
    const fvec4 bC = ntload_f4(bary + 12*p + 8);
    const fvec4 tA = ntload_f4(texels + 12*p + 0);
    const fvec4 tB = ntload_f4(texels + 12*p + 4);
    const fvec4 tC = ntload_f4(texels + 12*p + 8);
    const float vR = __builtin_nontemporal_load(vis + 3*p+0);
    const float vG = __builtin_nontemporal_load(vis + 3*p+1);
    const float vB = __builtin_nontemporal_load(vis + 3*p+2);

    const int fi[4] = {f4.x, f4.y, f4.z, f4.w};

    // per-batch uniforms
    const float llx = l_loc[3*n+0], lly = l_loc[3*n+1], llz = l_loc[3*n+2];
    const float ccx = cam[3*n+0],   ccy = cam[3*n+1],   ccz = cam[3*n+2];
    const float ambR = m_amb[3*n+0]*l_amb[3*n+0];
    const float ambG = m_amb[3*n+1]*l_amb[3*n+1];
    const float ambB = m_amb[3*n+2]*l_amb[3*n+2];
    const float kdR  = m_dif[3*n+0]*l_dif[3*n+0];
    const float kdG  = m_dif[3*n+1]*l_dif[3*n+1];
    const float kdB  = m_dif[3*n+2]*l_dif[3*n+2];
    const float ksR  = m_spec[3*n+0]*l_spec[3*n+0];
    const float ksG  = m_spec[3*n+1]*l_spec[3*n+1];
    const float ksB  = m_spec[3*n+2]*l_spec[3*n+2];
    const float shin = shininess[n];

    const float zb[4] = {z4.x, z4.y, z4.z, z4.w};
    const float dd[4] = {d4.x, d4.y, d4.z, d4.w};
    const float bc[12] = {bA.x,bA.y,bA.z,bA.w, bB.x,bB.y,bB.z,bB.w, bC.x,bC.y,bC.z,bC.w};
    const float tx[12] = {tA.x,tA.y,tA.z,tA.w, tB.x,tB.y,tB.z,tB.w, tC.x,tC.y,tC.z,tC.w};

    float colR[4], colG[4], colB[4], prob[4], zinv[4];
    float zmax = EPSB_C;

#pragma unroll
    for (int k = 0; k < 4; ++k) {
        const bool live = fi[k] >= 0;
        const int  f    = live ? fi[k] : 0;
        // single 80B record: 2 cache lines, 5 divergent loads (vs 7 instr / ~7 lines)
        const float* rec = table + (size_t)f * REC_F;
        const fvec4 r0 = *reinterpret_cast<const fvec4*>(rec + 0);
        const fvec4 r1 = *reinterpret_cast<const fvec4*>(rec + 4);
        const fvec4 r2 = *reinterpret_cast<const fvec4*>(rec + 8);
        const fvec4 r3 = *reinterpret_cast<const fvec4*>(rec + 12);
        const fvec2 r4 = *reinterpret_cast<const fvec2*>(rec + 16);

        const float b0 = bc[3*k+0], b1 = bc[3*k+1], b2 = bc[3*k+2];

        const float pcx = b0*r0.x + b1*r0.w + b2*r1.z;
        const float pcy = b0*r0.y + b1*r1.x + b2*r1.w;
        const float pcz = b0*r0.z + b1*r1.y + b2*r2.x;

        const float pnx = b0*r2.y + b1*r3.x + b2*r3.w;
        const float pny = b0*r2.z + b1*r3.y + b2*r4.x;
        const float pnz = b0*r2.w + b1*r3.z + b2*r4.y;

        const float nl  = sqrtf(pnx*pnx + pny*pny + pnz*pnz);
        const float inl = 1.0f / fmaxf(nl, 1e-6f);
        const float nx = pnx*inl, ny = pny*inl, nz = pnz*inl;

        float dx = llx - pcx, dy = lly - pcy, dz = llz - pcz;
        const float dl  = sqrtf(dx*dx + dy*dy + dz*dz);
        const float idl = 1.0f / fmaxf(dl, 1e-6f);
        dx *= idl; dy *= idl; dz *= idl;

        const float cosang = nx*dx + ny*dy + nz*dz;
        const float rcos   = fmaxf(cosang, 0.0f);

        const float rx = 2.0f*cosang*nx - dx;
        const float ry = 2.0f*cosang*ny - dy;
        const float rz = 2.0f*cosang*nz - dz;

        float vx = ccx - pcx, vy = ccy - pcy, vz = ccz - pcz;
        const float vl  = sqrtf(vx*vx + vy*vy + vz*vz);
        const float ivl = 1.0f / fmaxf(vl, 1e-6f);
        vx *= ivl; vy *= ivl; vz *= ivl;

        const float sdot = vx*rx + vy*ry + vz*rz;
        const float spec_cos = (cosang > 0.0f) ? fmaxf(sdot, 0.0f) : 0.0f;
        const float sp = (spec_cos > 0.0f) ? exp2f(shin * log2f(spec_cos)) : 0.0f;

        colR[k] = (ambR + kdR*rcos*vR) * tx[3*k+0] + ksR*sp;
        colG[k] = (ambG + kdG*rcos*vG) * tx[3*k+1] + ksG*sp;
        colB[k] = (ambB + kdB*rcos*vB) * tx[3*k+2] + ksB*sp;

        prob[k] = live ? 1.0f / (1.0f + __expf(dd[k] / SIGMA_C)) : 0.0f;
        zinv[k] = live ? (ZFAR_C - zb[k]) / (ZFAR_C - ZNEAR_C)  : 0.0f;
        zmax = fmaxf(zmax, zinv[k]);
    }

    const float delta = __expf((EPSB_C - zmax) / GAMMA_C);
    float denom = delta;
    float accR = delta, accG = delta, accB = delta;   // delta * BG(1,1,1)
    float keep = 1.0f;
#pragma unroll
    for (int k = 0; k < 4; ++k) {
        const float w = prob[k] * __expf((zinv[k] - zmax) / GAMMA_C);
        denom += w;
        accR += w * colR[k];
        accG += w * colG[k];
        accB += w * colB[k];
        keep *= (1.0f - prob[k]);
    }
    const float inv = 1.0f / denom;
    fvec4 res; res.x = accR*inv; res.y = accG*inv; res.z = accB*inv; res.w = 1.0f - keep;
    __builtin_nontemporal_store(res, reinterpret_cast<fvec4*>(out) + p);
}

// ---------------- Fallback (direct gather, R3 structure) ----------------
__global__ __launch_bounds__(256) void soft_phong_direct(
    const float* __restrict__ verts,
    const float* __restrict__ vnorm,
    const float* __restrict__ bary,
    const float* __restrict__ zbuf,
    const float* __restrict__ dists,
    const float* __restrict__ texels,
    const float* __restrict__ vis,
    const float* __restrict__ l_loc,
    const float* __restrict__ l_amb,
    const float* __restrict__ l_dif,
    const float* __restrict__ l_spec,
    const float* __restrict__ cam,
    const float* __restrict__ m_amb,
    const float* __restrict__ m_dif,
    const float* __restrict__ m_spec,
    const float* __restrict__ shininess,
    const int*   __restrict__ faces,
    const int*   __restrict__ p2f,
    float* __restrict__ out)
{
    const int p = blockIdx.x * 256 + threadIdx.x;
    const int n = p >> HW_SHIFT;
    const ivec4 f4 = ntload_i4(p2f + 4*p);
    const fvec4 z4 = ntload_f4(zbuf + 4*p);
    const fvec4 d4 = ntload_f4(dists + 4*p);
    const fvec4 bA = ntload_f4(bary + 12*p + 0);
    const fvec4 bB = ntload_f4(bary + 12*p + 4);
    const fvec4 bC = ntload_f4(bary + 12*p + 8);
    const fvec4 tA = ntload_f4(texels + 12*p + 0);
    const fvec4 tB = ntload_f4(texels + 12*p + 4);
    const fvec4 tC = ntload_f4(texels + 12*p + 8);
    const float vR = vis[3*p+0], vG = vis[3*p+1], vB = vis[3*p+2];
    const int fi[4] = {f4.x, f4.y, f4.z, f4.w};
    I3 fidx[4];
#pragma unroll
    for (int k = 0; k < 4; ++k) {
        const int f = (fi[k] >= 0) ? fi[k] : 0;
        fidx[k] = reinterpret_cast<const I3*>(faces)[f];
    }
    F3 vp[4][3], vn[4][3];
#pragma unroll
    for (int k = 0; k < 4; ++k) {
        const int i0 = fidx[k].x, i1 = fidx[k].y, i2 = fidx[k].z;
        vp[k][0] = reinterpret_cast<const F3*>(verts)[i0];
        vp[k][1] = reinterpret_cast<const F3*>(verts)[i1];
        vp[k][2] = reinterpret_cast<const F3*>(verts)[i2];
        vn[k][0] = reinterpret_cast<const F3*>(vnorm)[i0];
        vn[k][1] = reinterpret_cast<const F3*>(vnorm)[i1];
        vn[k][2] = reinterpret_cast<const F3*>(vnorm)[i2];
    }
    const float llx = l_loc[3*n+0], lly = l_loc[3*n+1], llz = l_loc[3*n+2];
    const float ccx = cam[3*n+0],   ccy = cam[3*n+1],   ccz = cam[3*n+2];
    const float ambR = m_amb[3*n+0]*l_amb[3*n+0];
    const float ambG = m_amb[3*n+1]*l_amb[3*n+1];
    const float ambB = m_amb[3*n+2]*l_amb[3*n+2];
    const float kdR  = m_dif[3*n+0]*l_dif[3*n+0];
    const float kdG  = m_dif[3*n+1]*l_dif[3*n+1];
    const float kdB  = m_dif[3*n+2]*l_dif[3*n+2];
    const float ksR  = m_spec[3*n+0]*l_spec[3*n+0];
    const float ksG  = m_spec[3*n+1]*l_spec[3*n+1];
    const float ksB  = m_spec[3*n+2]*l_spec[3*n+2];
    const float shin = shininess[n];
    const float zb[4] = {z4.x, z4.y, z4.z, z4.w};
    const float dd[4] = {d4.x, d4.y, d4.z, d4.w};
    const float bc[12] = {bA.x,bA.y,bA.z,bA.w, bB.x,bB.y,bB.z,bB.w, bC.x,bC.y,bC.z,bC.w};
    const float tx[12] = {tA.x,tA.y,tA.z,tA.w, tB.x,tB.y,tB.z,tB.w, tC.x,tC.y,tC.z,tC.w};
    float colR[4], colG[4], colB[4], prob[4], zinv[4];
    float zmax = EPSB_C;
#pragma unroll
    for (int k = 0; k < 4; ++k) {
        const bool live = fi[k] >= 0;
        const float b0 = bc[3*k+0], b1 = bc[3*k+1], b2 = bc[3*k+2];
        const float pcx = b0*vp[k][0].x + b1*vp[k][1].x + b2*vp[k][2].x;
        const float pcy = b0*vp[k][0].y + b1*vp[k][1].y + b2*vp[k][2].y;
        const float pcz = b0*vp[k][0].z + b1*vp[k][1].z + b2*vp[k][2].z;
        const float pnx = b0*vn[k][0].x + b1*vn[k][1].x + b2*vn[k][2].x;
        const float pny = b0*vn[k][0].y + b1*vn[k][1].y + b2*vn[k][2].y;
        const float pnz = b0*vn[k][0].z + b1*vn[k][1].z + b2*vn[k][2].z;
        const float nl  = sqrtf(pnx*pnx + pny*pny + pnz*pnz);
        const float inl = 1.0f / fmaxf(nl, 1e-6f);
        const float nx = pnx*inl, ny = pny*inl, nz = pnz*inl;
        float dx = llx - pcx, dy = lly - pcy, dz = llz - pcz;
        const float dl  = sqrtf(dx*dx + dy*dy + dz*dz);
        const float idl = 1.0f / fmaxf(dl, 1e-6f);
        dx *= idl; dy *= idl; dz *= idl;
        const float cosang = nx*dx + ny*dy + nz*dz;
        const float rcos   = fmaxf(cosang, 0.0f);
        const float rx = 2.0f*cosang*nx - dx;
        const float ry = 2.0f*cosang*ny - dy;
        const float rz = 2.0f*cosang*nz - dz;
        float vx = ccx - pcx, vy = ccy - pcy, vz = ccz - pcz;
        const float vl  = sqrtf(vx*vx + vy*vy + vz*vz);
        const float ivl = 1.0f / fmaxf(vl, 1e-6f);
        vx *= ivl; vy *= ivl; vz *= ivl;
        const float sdot = vx*rx + vy*ry + vz*rz;
        const float spec_cos = (cosang > 0.0f) ? fmaxf(sdot, 0.0f) : 0.0f;
        const float sp = (spec_cos > 0.0f) ? exp2f(shin * log2f(spec_cos)) : 0.0f;
        colR[k] = (ambR + kdR*rcos*vR) * tx[3*k+0] + ksR*sp;
        colG[k] = (ambG + kdG*rcos*vG) * tx[3*k+1] + ksG*sp;
        colB[k] = (ambB + kdB*rcos*vB) * tx[3*k+2] + ksB*sp;
        prob[k] = live ? 1.0f / (1.0f + __expf(dd[k] / SIGMA_C)) : 0.0f;
        zinv[k] = live ? (ZFAR_C - zb[k]) / (ZFAR_C - ZNEAR_C)  : 0.0f;
        zmax = fmaxf(zmax, zinv[k]);
    }
    const float delta = __expf((EPSB_C - zmax) / GAMMA_C);
    float denom = delta;
    float accR = delta, accG = delta, accB = delta;
    float keep = 1.0f;
#pragma unroll
    for (int k = 0; k < 4; ++k) {
        const float w = prob[k] * __expf((zinv[k] - zmax) / GAMMA_C);
        denom += w;
        accR += w * colR[k];
        accG += w * colG[k];
        accB += w * colB[k];
        keep *= (1.0f - prob[k]);
    }
    const float inv = 1.0f / denom;
    fvec4 res; res.x = accR*inv; res.y = accG*inv; res.z = accB*inv; res.w = 1.0f - keep;
    __builtin_nontemporal_store(res, reinterpret_cast<fvec4*>(out) + p);
}

extern "C" void kernel_launch(void* const* d_in, const int* in_sizes, int n_in,
                              void* d_out, int out_size, void* d_ws, size_t ws_size,
                              hipStream_t stream) {
    const float* verts   = (const float*)d_in[0];
    const float* vnorm   = (const float*)d_in[1];
    const float* bary    = (const float*)d_in[2];
    const float* zbuf    = (const float*)d_in[3];
    const float* dists   = (const float*)d_in[4];
    const float* texels  = (const float*)d_in[5];
    const float* vis     = (const float*)d_in[6];
    const float* l_loc   = (const float*)d_in[7];
    const float* l_amb   = (const float*)d_in[8];
    const float* l_dif   = (const float*)d_in[9];
    const float* l_spec  = (const float*)d_in[10];
    const float* cam     = (const float*)d_in[11];
    const float* m_amb   = (const float*)d_in[12];
    const float* m_dif   = (const float*)d_in[13];
    const float* m_spec  = (const float*)d_in[14];
    const float* shin    = (const float*)d_in[15];
    const int*   faces   = (const int*)d_in[16];
    const int*   p2f     = (const int*)d_in[17];
    float* out = (float*)d_out;

    if (ws_size >= TABLE_BYTES) {
        float* table = (float*)d_ws;
        build_face_table<<<(F_ + 255) / 256, 256, 0, stream>>>(verts, vnorm, faces, table);
        soft_phong_kernel<<<NPIX / 256, 256, 0, stream>>>(
            table, bary, zbuf, dists, texels, vis,
            l_loc, l_amb, l_dif, l_spec, cam,
            m_amb, m_dif, m_spec, shin, p2f, out);
    } else {
        soft_phong_direct<<<NPIX / 256, 256, 0, stream>>>(
            verts, vnorm, bary, zbuf, dists, texels, vis,
            l_loc, l_amb, l_dif, l_spec, cam,
            m_amb, m_dif, m_spec, shin, faces, p2f, out);
    }
}

// Round 5
// 403.735 us; speedup vs baseline: 1.2356x; 1.0169x over previous
//
#include <hip/hip_runtime.h>
#include <math.h>

#define SIGMA_C   1e-4f
#define GAMMA_C   1e-4f
#define ZNEAR_C   1.0f
#define ZFAR_C    100.0f
#define EPSB_C    1e-10f

static constexpr int N_ = 8, H_ = 512, W_ = 512, K_ = 4;
static constexpr int NPIX = N_ * H_ * W_;     // 2,097,152
static constexpr int NSMP = NPIX * K_;        // 8,388,608
static constexpr int F_ = 100000;
static constexpr int REC_F = 20;              // floats per face record (80 B stride)
static constexpr size_t TABLE_BYTES = (size_t)F_ * REC_F * sizeof(float);

typedef float fvec4 __attribute__((ext_vector_type(4)));
typedef float fvec2 __attribute__((ext_vector_type(2)));

struct F3 { float x, y, z; };

__device__ __forceinline__ float ntf(const float* p) {
    return __builtin_nontemporal_load(p);
}

// ---------------- Phase 1: pack faces -> 80B records --------------------
// rec floats: [v0.xyz v1.x][v1.yz v2.xy][v2.z n0.xyz][n1.xyz n2.x][n2.yz][pad2]
__global__ __launch_bounds__(256) void build_face_table(
    const float* __restrict__ verts,
    const float* __restrict__ vnorm,
    const int*   __restrict__ faces,
    float* __restrict__ table)
{
    const int f = blockIdx.x * 256 + threadIdx.x;
    if (f >= F_) return;
    const int i0 = faces[3*f+0], i1 = faces[3*f+1], i2 = faces[3*f+2];
    const F3 a = reinterpret_cast<const F3*>(verts)[i0];
    const F3 b = reinterpret_cast<const F3*>(verts)[i1];
    const F3 c = reinterpret_cast<const F3*>(verts)[i2];
    const F3 p = reinterpret_cast<const F3*>(vnorm)[i0];
    const F3 q = reinterpret_cast<const F3*>(vnorm)[i1];
    const F3 r = reinterpret_cast<const F3*>(vnorm)[i2];
    float* o = table + (size_t)f * REC_F;
    fvec4 r0 = {a.x, a.y, a.z, b.x};
    fvec4 r1 = {b.y, b.z, c.x, c.y};
    fvec4 r2 = {c.z, p.x, p.y, p.z};
    fvec4 r3 = {q.x, q.y, q.z, r.x};
    fvec2 r4 = {r.y, r.z};
    *reinterpret_cast<fvec4*>(o + 0)  = r0;
    *reinterpret_cast<fvec4*>(o + 4)  = r1;
    *reinterpret_cast<fvec4*>(o + 8)  = r2;
    *reinterpret_cast<fvec4*>(o + 12) = r3;
    *reinterpret_cast<fvec2*>(o + 16) = r4;
}

// ---------------- Phase 2: one thread per (pixel, sample) ----------------
__global__ __launch_bounds__(256) void soft_phong_sample(
    const float* __restrict__ table,
    const float* __restrict__ bary,
    const float* __restrict__ zbuf,
    const float* __restrict__ dists,
    const float* __restrict__ texels,
    const float* __restrict__ vis,
    const float* __restrict__ l_loc,
    const float* __restrict__ l_amb,
    const float* __restrict__ l_dif,
    const float* __restrict__ l_spec,
    const float* __restrict__ cam,
    const float* __restrict__ m_amb,
    const float* __restrict__ m_dif,
    const float* __restrict__ m_spec,
    const float* __restrict__ shininess,
    const int*   __restrict__ p2f,
    float* __restrict__ out)
{
    const int s = blockIdx.x * 256 + threadIdx.x;  // sample index = 4*pixel + k
    const int p = s >> 2;
    const int k = s & 3;
    const int n = s >> 20;                         // batch (wave-uniform)

    // face index first -> gather chain starts ASAP
    const int  f0   = __builtin_nontemporal_load(p2f + s);
    const bool live = f0 >= 0;
    const int  f    = live ? f0 : 0;
    const float* rec = table + (size_t)f * REC_F;
    const fvec4 r0 = *reinterpret_cast<const fvec4*>(rec + 0);
    const fvec4 r1 = *reinterpret_cast<const fvec4*>(rec + 4);
    const fvec4 r2 = *reinterpret_cast<const fvec4*>(rec + 8);
    const fvec4 r3 = *reinterpret_cast<const fvec4*>(rec + 12);
    const fvec2 r4 = *reinterpret_cast<const fvec2*>(rec + 16);

    // streaming loads (all coalesced dwords across the wave)
    const float zb = ntf(zbuf + s);
    const float dd = ntf(dists + s);
    const float b0 = ntf(bary + 3*s+0), b1 = ntf(bary + 3*s+1), b2 = ntf(bary + 3*s+2);
    const float t0 = ntf(texels + 3*s+0), t1 = ntf(texels + 3*s+1), t2 = ntf(texels + 3*s+2);
    const float vR = vis[3*p+0], vG = vis[3*p+1], vB = vis[3*p+2];

    // per-batch uniforms (wave-uniform -> scalar)
    const float llx = l_loc[3*n+0], lly = l_loc[3*n+1], llz = l_loc[3*n+2];
    const float ccx = cam[3*n+0],   ccy = cam[3*n+1],   ccz = cam[3*n+2];
    const float ambR = m_amb[3*n+0]*l_amb[3*n+0];
    const float ambG = m_amb[3*n+1]*l_amb[3*n+1];
    const float ambB = m_amb[3*n+2]*l_amb[3*n+2];
    const float kdR  = m_dif[3*n+0]*l_dif[3*n+0];
    const float kdG  = m_dif[3*n+1]*l_dif[3*n+1];
    const float kdB  = m_dif[3*n+2]*l_dif[3*n+2];
    const float ksR  = m_spec[3*n+0]*l_spec[3*n+0];
    const float ksG  = m_spec[3*n+1]*l_spec[3*n+1];
    const float ksB  = m_spec[3*n+2]*l_spec[3*n+2];
    const float shin = shininess[n];

    // ---- shade this sample ----
    const float pcx = b0*r0.x + b1*r0.w + b2*r1.z;
    const float pcy = b0*r0.y + b1*r1.x + b2*r1.w;
    const float pcz = b0*r0.z + b1*r1.y + b2*r2.x;

    const float pnx = b0*r2.y + b1*r3.x + b2*r3.w;
    const float pny = b0*r2.z + b1*r3.y + b2*r4.x;
    const float pnz = b0*r2.w + b1*r3.z + b2*r4.y;

    const float nl  = sqrtf(pnx*pnx + pny*pny + pnz*pnz);
    const float inl = 1.0f / fmaxf(nl, 1e-6f);
    const float nx = pnx*inl, ny = pny*inl, nz = pnz*inl;

    float dx = llx - pcx, dy = lly - pcy, dz = llz - pcz;
    const float dl  = sqrtf(dx*dx + dy*dy + dz*dz);
    const float idl = 1.0f / fmaxf(dl, 1e-6f);
    dx *= idl; dy *= idl; dz *= idl;

    const float cosang = nx*dx + ny*dy + nz*dz;
    const float rcos   = fmaxf(cosang, 0.0f);

    const float rx = 2.0f*cosang*nx - dx;
    const float ry = 2.0f*cosang*ny - dy;
    const float rz = 2.0f*cosang*nz - dz;

    float vx = ccx - pcx, vy = ccy - pcy, vz = ccz - pcz;
    const float vl  = sqrtf(vx*vx + vy*vy + vz*vz);
    const float ivl = 1.0f / fmaxf(vl, 1e-6f);
    vx *= ivl; vy *= ivl; vz *= ivl;

    const float sdot = vx*rx + vy*ry + vz*rz;
    const float spec_cos = (cosang > 0.0f) ? fmaxf(sdot, 0.0f) : 0.0f;
    const float sp = (spec_cos > 0.0f) ? exp2f(shin * log2f(spec_cos)) : 0.0f;

    const float colR = (ambR + kdR*rcos*vR) * t0 + ksR*sp;
    const float colG = (ambG + kdG*rcos*vG) * t1 + ksG*sp;
    const float colB = (ambB + kdB*rcos*vB) * t2 + ksB*sp;

    const float prob = live ? 1.0f / (1.0f + __expf(dd / SIGMA_C)) : 0.0f;
    const float zinv = live ? (ZFAR_C - zb) / (ZFAR_C - ZNEAR_C)  : 0.0f;

    // ---- quad (4-lane) blend reduction via shuffle butterflies ----
    float zmax = zinv;
    zmax = fmaxf(zmax, __shfl_xor(zmax, 1));
    zmax = fmaxf(zmax, __shfl_xor(zmax, 2));
    zmax = fmaxf(zmax, EPSB_C);

    const float w = prob * __expf((zinv - zmax) / GAMMA_C);
    float aw = w, aR = w*colR, aG = w*colG, aB = w*colB, kp = 1.0f - prob;

    aw += __shfl_xor(aw, 1);  aR += __shfl_xor(aR, 1);
    aG += __shfl_xor(aG, 1);  aB += __shfl_xor(aB, 1);
    kp *= __shfl_xor(kp, 1);
    aw += __shfl_xor(aw, 2);  aR += __shfl_xor(aR, 2);
    aG += __shfl_xor(aG, 2);  aB += __shfl_xor(aB, 2);
    kp *= __shfl_xor(kp, 2);

    const float delta = __expf((EPSB_C - zmax) / GAMMA_C);
    const float inv   = 1.0f / (aw + delta);

    // lane k writes channel k -> out[4p+k] == out[s]; fully coalesced dwords
    float val;
    if      (k == 0) val = (aR + delta) * inv;
    else if (k == 1) val = (aG + delta) * inv;
    else if (k == 2) val = (aB + delta) * inv;
    else             val = 1.0f - kp;
    __builtin_nontemporal_store(val, out + s);
}

// ---------------- Fallback (direct per-pixel gather, R4 structure) -------
__global__ __launch_bounds__(256) void soft_phong_direct(
    const float* __restrict__ verts,
    const float* __restrict__ vnorm,
    const float* __restrict__ bary,
    const float* __restrict__ zbuf,
    const float* __restrict__ dists,
    const float* __restrict__ texels,
    const float* __restrict__ vis,
    const float* __restrict__ l_loc,
    const float* __restrict__ l_amb,
    const float* __restrict__ l_dif,
    const float* __restrict__ l_spec,
    const float* __restrict__ cam,
    const float* __restrict__ m_amb,
    const float* __restrict__ m_dif,
    const float* __restrict__ m_spec,
    const float* __restrict__ shininess,
    const int*   __restrict__ faces,
    const int*   __restrict__ p2f,
    float* __restrict__ out)
{
    const int p = blockIdx.x * 256 + threadIdx.x;
    const int n = p >> 18;
    struct I3 { int x, y, z; };
    const int fi[4] = {p2f[4*p+0], p2f[4*p+1], p2f[4*p+2], p2f[4*p+3]};
    I3 fidx[4];
#pragma unroll
    for (int k = 0; k < 4; ++k) {
        const int f = (fi[k] >= 0) ? fi[k] : 0;
        fidx[k] = reinterpret_cast<const I3*>(faces)[f];
    }
    F3 vp[4][3], vn[4][3];
#pragma unroll
    for (int k = 0; k < 4; ++k) {
        const int i0 = fidx[k].x, i1 = fidx[k].y, i2 = fidx[k].z;
        vp[k][0] = reinterpret_cast<const F3*>(verts)[i0];
        vp[k][1] = reinterpret_cast<const F3*>(verts)[i1];
        vp[k][2] = reinterpret_cast<const F3*>(verts)[i2];
        vn[k][0] = reinterpret_cast<const F3*>(vnorm)[i0];
        vn[k][1] = reinterpret_cast<const F3*>(vnorm)[i1];
        vn[k][2] = reinterpret_cast<const F3*>(vnorm)[i2];
    }
    const float llx = l_loc[3*n+0], lly = l_loc[3*n+1], llz = l_loc[3*n+2];
    const float ccx = cam[3*n+0],   ccy = cam[3*n+1],   ccz = cam[3*n+2];
    const float ambR = m_amb[3*n+0]*l_amb[3*n+0];
    const float ambG = m_amb[3*n+1]*l_amb[3*n+1];
    const float ambB = m_amb[3*n+2]*l_amb[3*n+2];
    const float kdR  = m_dif[3*n+0]*l_dif[3*n+0];
    const float kdG  = m_dif[3*n+1]*l_dif[3*n+1];
    const float kdB  = m_dif[3*n+2]*l_dif[3*n+2];
    const float ksR  = m_spec[3*n+0]*l_spec[3*n+0];
    const float ksG  = m_spec[3*n+1]*l_spec[3*n+1];
    const float ksB  = m_spec[3*n+2]*l_spec[3*n+2];
    const float shin = shininess[n];
    float colR[4], colG[4], colB[4], prob[4], zinv[4];
    float zmax = EPSB_C;
#pragma unroll
    for (int k = 0; k < 4; ++k) {
        const bool live = fi[k] >= 0;
        const float b0 = bary[12*p+3*k+0], b1 = bary[12*p+3*k+1], b2 = bary[12*p+3*k+2];
        const float pcx = b0*vp[k][0].x + b1*vp[k][1].x + b2*vp[k][2].x;
        const float pcy = b0*vp[k][0].y + b1*vp[k][1].y + b2*vp[k][2].y;
        const float pcz = b0*vp[k][0].z + b1*vp[k][1].z + b2*vp[k][2].z;
        const float pnx = b0*vn[k][0].x + b1*vn[k][1].x + b2*vn[k][2].x;
        const float pny = b0*vn[k][0].y + b1*vn[k][1].y + b2*vn[k][2].y;
        const float pnz = b0*vn[k][0].z + b1*vn[k][1].z + b2*vn[k][2].z;
        const float nl  = sqrtf(pnx*pnx + pny*pny + pnz*pnz);
        const float inl = 1.0f / fmaxf(nl, 1e-6f);
        const float nx = pnx*inl, ny = pny*inl, nz = pnz*inl;
        float dx = llx - pcx, dy = lly - pcy, dz = llz - pcz;
        const float dl  = sqrtf(dx*dx + dy*dy + dz*dz);
        const float idl = 1.0f / fmaxf(dl, 1e-6f);
        dx *= idl; dy *= idl; dz *= idl;
        const float cosang = nx*dx + ny*dy + nz*dz;
        const float rcos   = fmaxf(cosang, 0.0f);
        const float rx = 2.0f*cosang*nx - dx;
        const float ry = 2.0f*cosang*ny - dy;
        const float rz = 2.0f*cosang*nz - dz;
        float vx = ccx - pcx, vy = ccy - pcy, vz = ccz - pcz;
        const float vl  = sqrtf(vx*vx + vy*vy + vz*vz);
        const float ivl = 1.0f / fmaxf(vl, 1e-6f);
        vx *= ivl; vy *= ivl; vz *= ivl;
        const float sdot = vx*rx + vy*ry + vz*rz;
        const float spec_cos = (cosang > 0.0f) ? fmaxf(sdot, 0.0f) : 0.0f;
        const float sp = (spec_cos > 0.0f) ? exp2f(shin * log2f(spec_cos)) : 0.0f;
        const float vRl = vis[3*p+0], vGl = vis[3*p+1], vBl = vis[3*p+2];
        colR[k] = (ambR + kdR*rcos*vRl) * texels[12*p+3*k+0] + ksR*sp;
        colG[k] = (ambG + kdG*rcos*vGl) * texels[12*p+3*k+1] + ksG*sp;
        colB[k] = (ambB + kdB*rcos*vBl) * texels[12*p+3*k+2] + ksB*sp;
        prob[k] = live ? 1.0f / (1.0f + __expf(dists[4*p+k] / SIGMA_C)) : 0.0f;
        zinv[k] = live ? (ZFAR_C - zbuf[4*p+k]) / (ZFAR_C - ZNEAR_C)  : 0.0f;
        zmax = fmaxf(zmax, zinv[k]);
    }
    const float delta = __expf((EPSB_C - zmax) / GAMMA_C);
    float denom = delta, accR = delta, accG = delta, accB = delta, keep = 1.0f;
#pragma unroll
    for (int k = 0; k < 4; ++k) {
        const float w = prob[k] * __expf((zinv[k] - zmax) / GAMMA_C);
        denom += w; accR += w*colR[k]; accG += w*colG[k]; accB += w*colB[k];
        keep *= (1.0f - prob[k]);
    }
    const float inv = 1.0f / denom;
    out[4*p+0] = accR*inv; out[4*p+1] = accG*inv; out[4*p+2] = accB*inv; out[4*p+3] = 1.0f - keep;
}

extern "C" void kernel_launch(void* const* d_in, const int* in_sizes, int n_in,
                              void* d_out, int out_size, void* d_ws, size_t ws_size,
                              hipStream_t stream) {
    const float* verts   = (const float*)d_in[0];
    const float* vnorm   = (const float*)d_in[1];
    const float* bary    = (const float*)d_in[2];
    const float* zbuf    = (const float*)d_in[3];
    const float* dists   = (const float*)d_in[4];
    const float* texels  = (const float*)d_in[5];
    const float* vis     = (const float*)d_in[6];
    const float* l_loc   = (const float*)d_in[7];
    const float* l_amb   = (const float*)d_in[8];
    const float* l_dif   = (const float*)d_in[9];
    const float* l_spec  = (const float*)d_in[10];
    const float* cam     = (const float*)d_in[11];
    const float* m_amb   = (const float*)d_in[12];
    const float* m_dif   = (const float*)d_in[13];
    const float* m_spec  = (const float*)d_in[14];
    const float* shin    = (const float*)d_in[15];
    const int*   faces   = (const int*)d_in[16];
    const int*   p2f     = (const int*)d_in[17];
    float* out = (float*)d_out;

    if (ws_size >= TABLE_BYTES) {
        float* table = (float*)d_ws;
        build_face_table<<<(F_ + 255) / 256, 256, 0, stream>>>(verts, vnorm, faces, table);
        soft_phong_sample<<<NSMP / 256, 256, 0, stream>>>(
            table, bary, zbuf, dists, texels, vis,
            l_loc, l_amb, l_dif, l_spec, cam,
            m_amb, m_dif, m_spec, shin, p2f, out);
    } else {
        soft_phong_direct<<<NPIX / 256, 256, 0, stream>>>(
            verts, vnorm, bary, zbuf, dists, texels, vis,
            l_loc, l_amb, l_dif, l_spec, cam,
            m_amb, m_dif, m_spec, shin, faces, p2f, out);
    }
}

// Round 6
// 378.564 us; speedup vs baseline: 1.3178x; 1.0665x over previous
//
#include <hip/hip_runtime.h>
#include <math.h>

#define SIGMA_C   1e-4f
#define GAMMA_C   1e-4f
#define ZNEAR_C   1.0f
#define ZFAR_C    100.0f
#define EPSB_C    1e-10f

static constexpr int N_ = 8, H_ = 512, W_ = 512, K_ = 4;
static constexpr int NPIX = N_ * H_ * W_;     // 2,097,152
static constexpr int NSMP = NPIX * K_;        // 8,388,608
static constexpr int F_ = 100000;
static constexpr int REC_U = 16;              // uints per record (64 B stride, 64B-aligned)
static constexpr size_t TABLE_BYTES = (size_t)F_ * REC_U * sizeof(unsigned int); // 6.4 MB

typedef float        fvec4 __attribute__((ext_vector_type(4)));
typedef float        fvec2 __attribute__((ext_vector_type(2)));
typedef unsigned int uvec4 __attribute__((ext_vector_type(4)));
typedef unsigned int uvec2 __attribute__((ext_vector_type(2)));
typedef _Float16     hvec2 __attribute__((ext_vector_type(2)));

struct F3 { float x, y, z; };

__device__ __forceinline__ float ntf(const float* p) {
    return __builtin_nontemporal_load(p);
}
__device__ __forceinline__ unsigned int packh(float lo, float hi) {
    hvec2 h; h.x = (_Float16)lo; h.y = (_Float16)hi;
    return __builtin_bit_cast(unsigned int, h);
}
__device__ __forceinline__ hvec2 unpackh(unsigned int u) {
    return __builtin_bit_cast(hvec2, u);
}

// ---------------- Phase 1: pack faces -> 64B records --------------------
// rec (16 dwords): [n0.x n0.y n0.z n1.x][n1.y n1.z n2.x n2.y]
//                  [n2.z h(v0x,v0y) h(v0z,v1x) h(v1y,v1z)][h(v2x,v2y) h(v2z,0) pad pad]
// normals fp32 (1/|pn| + ^shininess amplification forbids compression);
// verts fp16 (benign error path). 1 cache line, 4 divergent loads per sample.
__global__ __launch_bounds__(256) void build_face_table(
    const float* __restrict__ verts,
    const float* __restrict__ vnorm,
    const int*   __restrict__ faces,
    unsigned int* __restrict__ table)
{
    const int f = blockIdx.x * 256 + threadIdx.x;
    if (f >= F_) return;
    const int i0 = faces[3*f+0], i1 = faces[3*f+1], i2 = faces[3*f+2];
    const F3 a = reinterpret_cast<const F3*>(verts)[i0];
    const F3 b = reinterpret_cast<const F3*>(verts)[i1];
    const F3 c = reinterpret_cast<const F3*>(verts)[i2];
    const F3 p = reinterpret_cast<const F3*>(vnorm)[i0];
    const F3 q = reinterpret_cast<const F3*>(vnorm)[i1];
    const F3 r = reinterpret_cast<const F3*>(vnorm)[i2];
    unsigned int* o = table + (size_t)f * REC_U;
    fvec4 A; A.x = p.x; A.y = p.y; A.z = p.z; A.w = q.x;
    fvec4 B; B.x = q.y; B.y = q.z; B.z = r.x; B.w = r.y;
    uvec4 C; C.x = __builtin_bit_cast(unsigned int, r.z);
    C.y = packh(a.x, a.y); C.z = packh(a.z, b.x); C.w = packh(b.y, b.z);
    uvec4 D; D.x = packh(c.x, c.y); D.y = packh(c.z, 0.0f); D.z = 0u; D.w = 0u;
    *reinterpret_cast<fvec4*>(o + 0)  = A;
    *reinterpret_cast<fvec4*>(o + 4)  = B;
    *reinterpret_cast<uvec4*>(o + 8)  = C;
    *reinterpret_cast<uvec4*>(o + 12) = D;   // full-width store; pad dwords unused
}

// ---------------- Phase 2: one thread per (pixel, sample) ----------------
__global__ __launch_bounds__(256) void soft_phong_sample(
    const unsigned int* __restrict__ table,
    const float* __restrict__ bary,
    const float* __restrict__ zbuf,
    const float* __restrict__ dists,
    const float* __restrict__ texels,
    const float* __restrict__ vis,
    const float* __restrict__ l_loc,
    const float* __restrict__ l_amb,
    const float* __restrict__ l_dif,
    const float* __restrict__ l_spec,
    const float* __restrict__ cam,
    const float* __restrict__ m_amb,
    const float* __restrict__ m_dif,
    const float* __restrict__ m_spec,
    const float* __restrict__ shininess,
    const int*   __restrict__ p2f,
    float* __restrict__ out)
{
    const int s = blockIdx.x * 256 + threadIdx.x;  // sample index = 4*pixel + k
    const int p = s >> 2;
    const int k = s & 3;
    const int n = s >> 20;                         // batch (wave-uniform)

    // face index first -> gather chain starts ASAP
    const int  f0   = __builtin_nontemporal_load(p2f + s);
    const bool live = f0 >= 0;
    const int  f    = live ? f0 : 0;
    const unsigned int* rec = table + (size_t)f * REC_U;
    const fvec4 A = *reinterpret_cast<const fvec4*>(rec + 0);
    const fvec4 B = *reinterpret_cast<const fvec4*>(rec + 4);
    const uvec4 C = *reinterpret_cast<const uvec4*>(rec + 8);
    const uvec2 D = *reinterpret_cast<const uvec2*>(rec + 12);

    // streaming loads (all coalesced dwords across the wave)
    const float zb = ntf(zbuf + s);
    const float dd = ntf(dists + s);
    const float b0 = ntf(bary + 3*s+0), b1 = ntf(bary + 3*s+1), b2 = ntf(bary + 3*s+2);
    const float t0 = ntf(texels + 3*s+0), t1 = ntf(texels + 3*s+1), t2 = ntf(texels + 3*s+2);
    const float vR = vis[3*p+0], vG = vis[3*p+1], vB = vis[3*p+2];

    // per-batch uniforms (wave-uniform -> scalar)
    const float llx = l_loc[3*n+0], lly = l_loc[3*n+1], llz = l_loc[3*n+2];
    const float ccx = cam[3*n+0],   ccy = cam[3*n+1],   ccz = cam[3*n+2];
    const float ambR = m_amb[3*n+0]*l_amb[3*n+0];
    const float ambG = m_amb[3*n+1]*l_amb[3*n+1];
    const float ambB = m_amb[3*n+2]*l_amb[3*n+2];
    const float kdR  = m_dif[3*n+0]*l_dif[3*n+0];
    const float kdG  = m_dif[3*n+1]*l_dif[3*n+1];
    const float kdB  = m_dif[3*n+2]*l_dif[3*n+2];
    const float ksR  = m_spec[3*n+0]*l_spec[3*n+0];
    const float ksG  = m_spec[3*n+1]*l_spec[3*n+1];
    const float ksB  = m_spec[3*n+2]*l_spec[3*n+2];
    const float shin = shininess[n];

    // ---- unpack record ----
    const float n2z = __builtin_bit_cast(float, C.x);
    const hvec2 h0 = unpackh(C.y);   // v0x v0y
    const hvec2 h1 = unpackh(C.z);   // v0z v1x
    const hvec2 h2 = unpackh(C.w);   // v1y v1z
    const hvec2 h3 = unpackh(D.x);   // v2x v2y
    const hvec2 h4 = unpackh(D.y);   // v2z -
    const float v0x = (float)h0.x, v0y = (float)h0.y, v0z = (float)h1.x;
    const float v1x = (float)h1.y, v1y = (float)h2.x, v1z = (float)h2.y;
    const float v2x = (float)h3.x, v2y = (float)h3.y, v2z = (float)h4.x;

    // ---- shade this sample ----
    const float pcx = b0*v0x + b1*v1x + b2*v2x;
    const float pcy = b0*v0y + b1*v1y + b2*v2y;
    const float pcz = b0*v0z + b1*v1z + b2*v2z;

    const float pnx = b0*A.x + b1*A.w + b2*B.z;
    const float pny = b0*A.y + b1*B.x + b2*B.w;
    const float pnz = b0*A.z + b1*B.y + b2*n2z;

    const float nl  = sqrtf(pnx*pnx + pny*pny + pnz*pnz);
    const float inl = 1.0f / fmaxf(nl, 1e-6f);
    const float nx = pnx*inl, ny = pny*inl, nz = pnz*inl;

    float dx = llx - pcx, dy = lly - pcy, dz = llz - pcz;
    const float dl  = sqrtf(dx*dx + dy*dy + dz*dz);
    const float idl = 1.0f / fmaxf(dl, 1e-6f);
    dx *= idl; dy *= idl; dz *= idl;

    const float cosang = nx*dx + ny*dy + nz*dz;
    const float rcos   = fmaxf(cosang, 0.0f);

    const float rx = 2.0f*cosang*nx - dx;
    const float ry = 2.0f*cosang*ny - dy;
    const float rz = 2.0f*cosang*nz - dz;

    float vx = ccx - pcx, vy = ccy - pcy, vz = ccz - pcz;
    const float vl  = sqrtf(vx*vx + vy*vy + vz*vz);
    const float ivl = 1.0f / fmaxf(vl, 1e-6f);
    vx *= ivl; vy *= ivl; vz *= ivl;

    const float sdot = vx*rx + vy*ry + vz*rz;
    const float spec_cos = (cosang > 0.0f) ? fmaxf(sdot, 0.0f) : 0.0f;
    const float sp = (spec_cos > 0.0f) ? exp2f(shin * log2f(spec_cos)) : 0.0f;

    const float colR = (ambR + kdR*rcos*vR) * t0 + ksR*sp;
    const float colG = (ambG + kdG*rcos*vG) * t1 + ksG*sp;
    const float colB = (ambB + kdB*rcos*vB) * t2 + ksB*sp;

    const float prob = live ? 1.0f / (1.0f + __expf(dd / SIGMA_C)) : 0.0f;
    const float zinv = live ? (ZFAR_C - zb) / (ZFAR_C - ZNEAR_C)  : 0.0f;

    // ---- quad (4-lane) blend reduction via shuffle butterflies ----
    float zmax = zinv;
    zmax = fmaxf(zmax, __shfl_xor(zmax, 1));
    zmax = fmaxf(zmax, __shfl_xor(zmax, 2));
    zmax = fmaxf(zmax, EPSB_C);

    const float w = prob * __expf((zinv - zmax) / GAMMA_C);
    float aw = w, aR = w*colR, aG = w*colG, aB = w*colB, kp = 1.0f - prob;

    aw += __shfl_xor(aw, 1);  aR += __shfl_xor(aR, 1);
    aG += __shfl_xor(aG, 1);  aB += __shfl_xor(aB, 1);
    kp *= __shfl_xor(kp, 1);
    aw += __shfl_xor(aw, 2);  aR += __shfl_xor(aR, 2);
    aG += __shfl_xor(aG, 2);  aB += __shfl_xor(aB, 2);
    kp *= __shfl_xor(kp, 2);

    const float delta = __expf((EPSB_C - zmax) / GAMMA_C);
    const float inv   = 1.0f / (aw + delta);

    // lane k writes channel k -> out[4p+k] == out[s]; fully coalesced dwords
    float val;
    if      (k == 0) val = (aR + delta) * inv;
    else if (k == 1) val = (aG + delta) * inv;
    else if (k == 2) val = (aB + delta) * inv;
    else             val = 1.0f - kp;
    __builtin_nontemporal_store(val, out + s);
}

// ---------------- Fallback (direct per-pixel gather) --------------------
__global__ __launch_bounds__(256) void soft_phong_direct(
    const float* __restrict__ verts,
    const float* __restrict__ vnorm,
    const float* __restrict__ bary,
    const float* __restrict__ zbuf,
    const float* __restrict__ dists,
    const float* __restrict__ texels,
    const float* __restrict__ vis,
    const float* __restrict__ l_loc,
    const float* __restrict__ l_amb,
    const float* __restrict__ l_dif,
    const float* __restrict__ l_spec,
    const float* __restrict__ cam,
    const float* __restrict__ m_amb,
    const float* __restrict__ m_dif,
    const float* __restrict__ m_spec,
    const float* __restrict__ shininess,
    const int*   __restrict__ faces,
    const int*   __restrict__ p2f,
    float* __restrict__ out)
{
    const int p = blockIdx.x * 256 + threadIdx.x;
    const int n = p >> 18;
    struct I3 { int x, y, z; };
    const int fi[4] = {p2f[4*p+0], p2f[4*p+1], p2f[4*p+2], p2f[4*p+3]};
    I3 fidx[4];
#pragma unroll
    for (int k = 0; k < 4; ++k) {
        const int f = (fi[k] >= 0) ? fi[k] : 0;
        fidx[k] = reinterpret_cast<const I3*>(faces)[f];
    }
    F3 vp[4][3], vn[4][3];
#pragma unroll
    for (int k = 0; k < 4; ++k) {
        const int i0 = fidx[k].x, i1 = fidx[k].y, i2 = fidx[k].z;
        vp[k][0] = reinterpret_cast<const F3*>(verts)[i0];
        vp[k][1] = reinterpret_cast<const F3*>(verts)[i1];
        vp[k][2] = reinterpret_cast<const F3*>(verts)[i2];
        vn[k][0] = reinterpret_cast<const F3*>(vnorm)[i0];
        vn[k][1] = reinterpret_cast<const F3*>(vnorm)[i1];
        vn[k][2] = reinterpret_cast<const F3*>(vnorm)[i2];
    }
    const float llx = l_loc[3*n+0], lly = l_loc[3*n+1], llz = l_loc[3*n+2];
    const float ccx = cam[3*n+0],   ccy = cam[3*n+1],   ccz = cam[3*n+2];
    const float ambR = m_amb[3*n+0]*l_amb[3*n+0];
    const float ambG = m_amb[3*n+1]*l_amb[3*n+1];
    const float ambB = m_amb[3*n+2]*l_amb[3*n+2];
    const float kdR  = m_dif[3*n+0]*l_dif[3*n+0];
    const float kdG  = m_dif[3*n+1]*l_dif[3*n+1];
    const float kdB  = m_dif[3*n+2]*l_dif[3*n+2];
    const float ksR  = m_spec[3*n+0]*l_spec[3*n+0];
    const float ksG  = m_spec[3*n+1]*l_spec[3*n+1];
    const float ksB  = m_spec[3*n+2]*l_spec[3*n+2];
    const float shin = shininess[n];
    float colR[4], colG[4], colB[4], prob[4], zinv[4];
    float zmax = EPSB_C;
#pragma unroll
    for (int k = 0; k < 4; ++k) {
        const bool live = fi[k] >= 0;
        const float b0 = bary[12*p+3*k+0], b1 = bary[12*p+3*k+1], b2 = bary[12*p+3*k+2];
        const float pcx = b0*vp[k][0].x + b1*vp[k][1].x + b2*vp[k][2].x;
        const float pcy = b0*vp[k][0].y + b1*vp[k][1].y + b2*vp[k][2].y;
        const float pcz = b0*vp[k][0].z + b1*vp[k][1].z + b2*vp[k][2].z;
        const float pnx = b0*vn[k][0].x + b1*vn[k][1].x + b2*vn[k][2].x;
        const float pny = b0*vn[k][0].y + b1*vn[k][1].y + b2*vn[k][2].y;
        const float pnz = b0*vn[k][0].z + b1*vn[k][1].z + b2*vn[k][2].z;
        const float nl  = sqrtf(pnx*pnx + pny*pny + pnz*pnz);
        const float inl = 1.0f / fmaxf(nl, 1e-6f);
        const float nx = pnx*inl, ny = pny*inl, nz = pnz*inl;
        float dx = llx - pcx, dy = lly - pcy, dz = llz - pcz;
        const float dl  = sqrtf(dx*dx + dy*dy + dz*dz);
        const float idl = 1.0f / fmaxf(dl, 1e-6f);
        dx *= idl; dy *= idl; dz *= idl;
        const float cosang = nx*dx + ny*dy + nz*dz;
        const float rcos   = fmaxf(cosang, 0.0f);
        const float rx = 2.0f*cosang*nx - dx;
        const float ry = 2.0f*cosang*ny - dy;
        const float rz = 2.0f*cosang*nz - dz;
        float vx = ccx - pcx, vy = ccy - pcy, vz = ccz - pcz;
        const float vl  = sqrtf(vx*vx + vy*vy + vz*vz);
        const float ivl = 1.0f / fmaxf(vl, 1e-6f);
        vx *= ivl; vy *= ivl; vz *= ivl;
        const float sdot = vx*rx + vy*ry + vz*rz;
        const float spec_cos = (cosang > 0.0f) ? fmaxf(sdot, 0.0f) : 0.0f;
        const float sp = (spec_cos > 0.0f) ? exp2f(shin * log2f(spec_cos)) : 0.0f;
        const float vRl = vis[3*p+0], vGl = vis[3*p+1], vBl = vis[3*p+2];
        colR[k] = (ambR + kdR*rcos*vRl) * texels[12*p+3*k+0] + ksR*sp;
        colG[k] = (ambG + kdG*rcos*vGl) * texels[12*p+3*k+1] + ksG*sp;
        colB[k] = (ambB + kdB*rcos*vBl) * texels[12*p+3*k+2] + ksB*sp;
        prob[k] = live ? 1.0f / (1.0f + __expf(dists[4*p+k] / SIGMA_C)) : 0.0f;
        zinv[k] = live ? (ZFAR_C - zbuf[4*p+k]) / (ZFAR_C - ZNEAR_C)  : 0.0f;
        zmax = fmaxf(zmax, zinv[k]);
    }
    const float delta = __expf((EPSB_C - zmax) / GAMMA_C);
    float denom = delta, accR = delta, accG = delta, accB = delta, keep = 1.0f;
#pragma unroll
    for (int k = 0; k < 4; ++k) {
        const float w = prob[k] * __expf((zinv[k] - zmax) / GAMMA_C);
        denom += w; accR += w*colR[k]; accG += w*colG[k]; accB += w*colB[k];
        keep *= (1.0f - prob[k]);
    }
    const float inv = 1.0f / denom;
    out[4*p+0] = accR*inv; out[4*p+1] = accG*inv; out[4*p+2] = accB*inv; out[4*p+3] = 1.0f - keep;
}

extern "C" void kernel_launch(void* const* d_in, const int* in_sizes, int n_in,
                              void* d_out, int out_size, void* d_ws, size_t ws_size,
                              hipStream_t stream) {
    const float* verts   = (const float*)d_in[0];
    const float* vnorm   = (const float*)d_in[1];
    const float* bary    = (const float*)d_in[2];
    const float* zbuf    = (const float*)d_in[3];
    const float* dists   = (const float*)d_in[4];
    const float* texels  = (const float*)d_in[5];
    const float* vis     = (const float*)d_in[6];
    const float* l_loc   = (const float*)d_in[7];
    const float* l_amb   = (const float*)d_in[8];
    const float* l_dif   = (const float*)d_in[9];
    const float* l_spec  = (const float*)d_in[10];
    const float* cam     = (const float*)d_in[11];
    const float* m_amb   = (const float*)d_in[12];
    const float* m_dif   = (const float*)d_in[13];
    const float* m_spec  = (const float*)d_in[14];
    const float* shin    = (const float*)d_in[15];
    const int*   faces   = (const int*)d_in[16];
    const int*   p2f     = (const int*)d_in[17];
    float* out = (float*)d_out;

    if (ws_size >= TABLE_BYTES) {
        unsigned int* table = (unsigned int*)d_ws;
        build_face_table<<<(F_ + 255) / 256, 256, 0, stream>>>(verts, vnorm, faces, table);
        soft_phong_sample<<<NSMP / 256, 256, 0, stream>>>(
            table, bary, zbuf, dists, texels, vis,
            l_loc, l_amb, l_dif, l_spec, cam,
            m_amb, m_dif, m_spec, shin, p2f, out);
    } else {
        soft_phong_direct<<<NPIX / 256, 256, 0, stream>>>(
            verts, vnorm, bary, zbuf, dists, texels, vis,
            l_loc, l_amb, l_dif, l_spec, cam,
            m_amb, m_dif, m_spec, shin, faces, p2f, out);
    }
}